// Round 1
// baseline (1280.113 us; speedup 1.0000x reference)
//
#include <hip/hip_runtime.h>
#include <hip/hip_bf16.h>
#include <stdint.h>

// Problem: LSTM cell. B=8192, IN=2048, H=2048.
// gates = [input, h_prev] @ [Wf;Wi;Wg;Wo]^T + b  -> f,i,g,o -> c,h
// Strategy: bf16 MFMA GEMM (m97-style global_load_lds staging), fused LSTM epilogue.

#define BQ 8192
#define INF 2048
#define HH 2048
#define KK 4096   // IN + H

typedef __attribute__((ext_vector_type(8))) short short8;
typedef __attribute__((ext_vector_type(4))) float floatx4;

__device__ __forceinline__ unsigned short f2b(float f) {
    unsigned u = __float_as_uint(f);
    u += 0x7fff + ((u >> 16) & 1);   // round-to-nearest-even
    return (unsigned short)(u >> 16);
}
__device__ __forceinline__ float b2f(unsigned short s) {
    return __uint_as_float(((unsigned)s) << 16);
}

// ---- pack [input | h_prev] -> bf16 combined [8192][4096] ----
__global__ __launch_bounds__(256) void pack_combined(
    const float4* __restrict__ inp, const float4* __restrict__ hp,
    unsigned short* __restrict__ dst)
{
    const int PER = BQ * INF / 4;               // 4,194,304 float4 per source
    int v = blockIdx.x * 256 + threadIdx.x;
    int isH = v >= PER;
    int u = isH ? (v - PER) : v;
    float4 x = (isH ? hp : inp)[u];
    int b  = u >> 9;                            // 512 float4 per 2048-row
    int kk = (u & 511) << 2;
    size_t off = (size_t)b * KK + kk + (isH ? INF : 0);
    ushort4 y;
    y.x = f2b(x.x); y.y = f2b(x.y); y.z = f2b(x.z); y.w = f2b(x.w);
    *(ushort4*)(dst + off) = y;
}

// ---- pack Wf,Wi,Wg,Wo -> bf16 W [4*2048][4096] ----
__global__ __launch_bounds__(256) void pack_w(
    const float4* __restrict__ w0, const float4* __restrict__ w1,
    const float4* __restrict__ w2, const float4* __restrict__ w3,
    unsigned short* __restrict__ dst)
{
    const int PER = HH * KK / 4;                // 2,097,152 float4 per gate
    int v = blockIdx.x * 256 + threadIdx.x;
    int g = v / PER;                            // power-of-2 -> shift
    int u = v - g * PER;
    const float4* src = (g == 0) ? w0 : (g == 1) ? w1 : (g == 2) ? w2 : w3;
    float4 x = src[u];
    ushort4 y;
    y.x = f2b(x.x); y.y = f2b(x.y); y.z = f2b(x.z); y.w = f2b(x.w);
    *(ushort4*)(dst + (size_t)v * 4) = y;
}

// ---- fused GEMM + LSTM epilogue ----
// Block: 256 threads (4 waves). Tile: 64 batch-rows x 64 hidden-cols x 4 gates.
// Wave w computes gate w's 64x64 tile (4x4 MFMA 16x16x32 acc).
// LDS: staging sA(4KB)+sB(16KB) overlaid with epilogue gate buffer (32KB bf16).
__global__ __launch_bounds__(256) void lstm_fused(
    const unsigned short* __restrict__ A,   // combined bf16 [8192][4096]
    const unsigned short* __restrict__ W,   // bf16 [4*2048][4096]
    const float* __restrict__ cprev,
    const float* __restrict__ bf_, const float* __restrict__ bi_,
    const float* __restrict__ bg_, const float* __restrict__ bo_,
    float* __restrict__ out)
{
    __shared__ unsigned short smem[16384];  // 32 KB
    unsigned short* sA = smem;              // [64][32]
    unsigned short* sB = smem + 2048;       // [4][64][32]

    const int t    = threadIdx.x;
    const int wave = t >> 6;
    const int lane = t & 63;
    const int m0   = blockIdx.y << 6;       // batch offset
    const int n0   = blockIdx.x << 6;       // hidden offset

    // staging: wave ww stages rows [ww*16, ww*16+16); lane l -> row ww*16+l/4, col (l%4)*8
    const int srow = lane >> 2;
    const int scol = (lane & 3) << 3;
    const unsigned short* ag = A + (size_t)(m0 + wave * 16 + srow) * KK + scol;
    const unsigned short* wg0 = W + (size_t)(0 * HH + n0 + wave * 16 + srow) * KK + scol;
    const unsigned short* wg1 = W + (size_t)(1 * HH + n0 + wave * 16 + srow) * KK + scol;
    const unsigned short* wg2 = W + (size_t)(2 * HH + n0 + wave * 16 + srow) * KK + scol;
    const unsigned short* wg3 = W + (size_t)(3 * HH + n0 + wave * 16 + srow) * KK + scol;

    floatx4 acc[4][4];
#pragma unroll
    for (int i = 0; i < 4; ++i)
#pragma unroll
        for (int j = 0; j < 4; ++j) acc[i][j] = (floatx4)0.f;

    const int fr = lane & 15;   // fragment row
    const int fq = lane >> 4;   // quad -> k-chunk

    for (int k0 = 0; k0 < KK; k0 += 32) {
        __builtin_amdgcn_global_load_lds(
            (const __attribute__((address_space(1))) void*)(ag + k0),
            (__attribute__((address_space(3))) void*)(sA + wave * 512), 16, 0, 0);
        __builtin_amdgcn_global_load_lds(
            (const __attribute__((address_space(1))) void*)(wg0 + k0),
            (__attribute__((address_space(3))) void*)(sB + 0 * 2048 + wave * 512), 16, 0, 0);
        __builtin_amdgcn_global_load_lds(
            (const __attribute__((address_space(1))) void*)(wg1 + k0),
            (__attribute__((address_space(3))) void*)(sB + 1 * 2048 + wave * 512), 16, 0, 0);
        __builtin_amdgcn_global_load_lds(
            (const __attribute__((address_space(1))) void*)(wg2 + k0),
            (__attribute__((address_space(3))) void*)(sB + 2 * 2048 + wave * 512), 16, 0, 0);
        __builtin_amdgcn_global_load_lds(
            (const __attribute__((address_space(1))) void*)(wg3 + k0),
            (__attribute__((address_space(3))) void*)(sB + 3 * 2048 + wave * 512), 16, 0, 0);
        __syncthreads();

        short8 af[4], bfr[4];
#pragma unroll
        for (int i = 0; i < 4; ++i) {
            af[i]  = *(const short8*)(sA + (i * 16 + fr) * 32 + fq * 8);
            bfr[i] = *(const short8*)(sB + wave * 2048 + (i * 16 + fr) * 32 + fq * 8);
        }
#pragma unroll
        for (int i = 0; i < 4; ++i)
#pragma unroll
            for (int j = 0; j < 4; ++j)
                acc[i][j] = __builtin_amdgcn_mfma_f32_16x16x32_bf16(
                    af[i], bfr[j], acc[i][j], 0, 0, 0);
        __syncthreads();
    }

    // epilogue: bias + activation, store bf16 tile to LDS (wave w = gate w)
    unsigned short* gbuf = smem;  // [4][64][64] bf16 = 32 KB
    const float* bias = (wave == 0) ? bf_ : (wave == 1) ? bi_ : (wave == 2) ? bg_ : bo_;
#pragma unroll
    for (int j = 0; j < 4; ++j) {
        int col = j * 16 + fr;
        float bv = bias[n0 + col];
#pragma unroll
        for (int i = 0; i < 4; ++i) {
            floatx4 v = acc[i][j];
#pragma unroll
            for (int r = 0; r < 4; ++r) {
                float x = v[r] + bv;
                float a = (wave == 2) ? tanhf(x) : 1.f / (1.f + __expf(-x));
                int row = i * 16 + fq * 4 + r;
                gbuf[wave * 4096 + row * 64 + col] = f2b(a);
            }
        }
    }
    __syncthreads();

    // combine: c = f*c_prev + i*g ; h = o*tanh(c)
#pragma unroll
    for (int i = 0; i < 16; ++i) {
        int e   = i * 256 + t;
        int row = e >> 6, col = e & 63;
        float f  = b2f(gbuf[        row * 64 + col]);
        float ii = b2f(gbuf[ 4096 + row * 64 + col]);
        float g  = b2f(gbuf[ 8192 + row * 64 + col]);
        float o  = b2f(gbuf[12288 + row * 64 + col]);
        size_t gi = (size_t)(m0 + row) * HH + (n0 + col);
        float c = f * cprev[gi] + ii * g;
        float h = o * tanhf(c);
        out[gi] = h;
        out[(size_t)BQ * HH + gi] = c;
    }
}

extern "C" void kernel_launch(void* const* d_in, const int* in_sizes, int n_in,
                              void* d_out, int out_size, void* d_ws, size_t ws_size,
                              hipStream_t stream) {
    const float* input  = (const float*)d_in[0];
    const float* h_prev = (const float*)d_in[1];
    const float* c_prev = (const float*)d_in[2];
    const float* Wf = (const float*)d_in[3];
    const float* bf_ = (const float*)d_in[4];
    const float* Wi = (const float*)d_in[5];
    const float* bi_ = (const float*)d_in[6];
    const float* Wg = (const float*)d_in[7];
    const float* bg_ = (const float*)d_in[8];
    const float* Wo = (const float*)d_in[9];
    const float* bo_ = (const float*)d_in[10];
    float* out = (float*)d_out;

    unsigned short* combined = (unsigned short*)d_ws;                   // 67,108,864 B
    unsigned short* Wpk = (unsigned short*)d_ws + (size_t)BQ * KK;      // 67,108,864 B
    // requires ws_size >= 134,217,728

    pack_combined<<<dim3(2 * BQ * INF / 4 / 256), 256, 0, stream>>>(
        (const float4*)input, (const float4*)h_prev, combined);
    pack_w<<<dim3(4 * HH * KK / 4 / 256), 256, 0, stream>>>(
        (const float4*)Wf, (const float4*)Wi, (const float4*)Wg, (const float4*)Wo, Wpk);
    lstm_fused<<<dim3(HH / 64, BQ / 64), 256, 0, stream>>>(
        combined, Wpk, c_prev, bf_, bi_, bg_, bo_, out);
}

// Round 2
// 1166.445 us; speedup vs baseline: 1.0974x; 1.0974x over previous
//
#include <hip/hip_runtime.h>
#include <hip/hip_bf16.h>
#include <stdint.h>

// LSTM cell. B=8192, IN=2048, H=2048.
// gates = [input,h_prev] @ [Wf;Wi;Wg;Wo]^T + b -> f,i,g,o -> c,h
// R2: m97-style 128x128 GEMM tile, BK=64 (two 32-wide sub-regions, one barrier
// pair per 64-K), gate-interleaved W packing so the LSTM epilogue fuses per-block.

#define BQ 8192
#define INF 2048
#define HH 2048
#define KK 4096   // IN + H

typedef __attribute__((ext_vector_type(8))) short short8;
typedef __attribute__((ext_vector_type(8))) unsigned short ushort8;
typedef __attribute__((ext_vector_type(4))) float floatx4;

__device__ __forceinline__ unsigned short f2b(float f) {
    unsigned u = __float_as_uint(f);
    u += 0x7fff + ((u >> 16) & 1);   // round-to-nearest-even
    return (unsigned short)(u >> 16);
}
__device__ __forceinline__ float b2f(unsigned short s) {
    return __uint_as_float(((unsigned)s) << 16);
}
__device__ __forceinline__ ushort8 cvt8(float4 a, float4 b) {
    ushort8 y;
    y[0] = f2b(a.x); y[1] = f2b(a.y); y[2] = f2b(a.z); y[3] = f2b(a.w);
    y[4] = f2b(b.x); y[5] = f2b(b.y); y[6] = f2b(b.z); y[7] = f2b(b.w);
    return y;
}

// ---- pack [input | h_prev] -> bf16 combined [8192][4096], 8 elems/thread ----
__global__ __launch_bounds__(256) void pack_combined(
    const float4* __restrict__ inp, const float4* __restrict__ hp,
    unsigned short* __restrict__ dst)
{
    const int PER8 = BQ * INF / 8;              // 2,097,152 threads per source
    int v = blockIdx.x * 256 + threadIdx.x;
    int isH = v >= PER8;
    int u8 = (isH ? (v - PER8) : v);
    const float4* src = isH ? hp : inp;
    float4 x0 = src[u8 * 2];
    float4 x1 = src[u8 * 2 + 1];
    int u = u8 * 8;
    int b = u >> 11;                            // 2048 elems per source row
    int k = u & 2047;
    size_t off = (size_t)b * KK + k + (isH ? INF : 0);
    *(ushort8*)(dst + off) = cvt8(x0, x1);
}

// ---- pack Wf..Wo -> bf16 W [8192][4096], gate-interleaved rows ----
// packed row p = (h>>5)*128 + gate*32 + (h&31)
__global__ __launch_bounds__(256) void pack_w(
    const float4* __restrict__ w0, const float4* __restrict__ w1,
    const float4* __restrict__ w2, const float4* __restrict__ w3,
    unsigned short* __restrict__ dst)
{
    int v = blockIdx.x * 256 + threadIdx.x;     // 4,194,304 threads
    size_t e = (size_t)v * 8;
    int g = (int)(e >> 23);                     // 2048*4096 = 2^23 per gate
    int u = (int)(e & ((1u << 23) - 1));
    int h = u >> 12;                            // 4096 per row
    int k = u & 4095;
    const float4* src = (g == 0) ? w0 : (g == 1) ? w1 : (g == 2) ? w2 : w3;
    float4 x0 = src[u >> 2];
    float4 x1 = src[(u >> 2) + 1];
    int p = ((h >> 5) << 7) + (g << 5) + (h & 31);
    *(ushort8*)(dst + (size_t)p * KK + k) = cvt8(x0, x1);
}

// ---- fused GEMM + LSTM epilogue ----
// Block: 256 threads (4 waves, 2x2 wave grid). Tile: 128(batch) x 128(packed-N).
// Packed-N tile = 32 hidden cols x 4 gates (interleaved) -> fused epilogue.
// BK=64 as two 32-col sub-regions; LDS 32 KB (staging 16K+16K overlaid w/ gbuf).
__global__ __launch_bounds__(256) void lstm_fused(
    const unsigned short* __restrict__ A,   // combined bf16 [8192][4096]
    const unsigned short* __restrict__ W,   // packed bf16 [8192][4096]
    const float* __restrict__ cprev,
    const float* __restrict__ bf_, const float* __restrict__ bi_,
    const float* __restrict__ bg_, const float* __restrict__ bo_,
    float* __restrict__ out)
{
    __shared__ unsigned short smem[16384];  // 32 KB
    unsigned short* sA = smem;              // [2][128][32] (kc-major)
    unsigned short* sB = smem + 8192;       // [2][128][32]

    const int t    = threadIdx.x;
    const int wave = t >> 6;
    const int lane = t & 63;
    const int wm   = wave >> 1;
    const int wn   = wave & 1;
    const int m0   = blockIdx.y << 7;       // batch offset (128 rows)
    const int n0   = blockIdx.x << 7;       // packed-row offset (128)
    const int h0   = blockIdx.x << 5;       // hidden col base (32)

    // staging: wave w stages rows [w*32, w*32+32) of A and B, for each kc.
    const int srow = lane >> 2;             // 0..15
    const int scol = (lane & 3) << 3;       // 0,8,16,24
    const unsigned short* aBase = A + (size_t)(m0 + wave * 32 + srow) * KK + scol;
    const unsigned short* bBase = W + (size_t)(n0 + wave * 32 + srow) * KK + scol;

    floatx4 acc[4][4];
#pragma unroll
    for (int i = 0; i < 4; ++i)
#pragma unroll
        for (int j = 0; j < 4; ++j) acc[i][j] = (floatx4)0.f;

    const int fr = lane & 15;   // fragment m/n index
    const int fq = lane >> 4;   // quad -> k-chunk

    for (int k0 = 0; k0 < KK; k0 += 64) {
#pragma unroll
        for (int kc = 0; kc < 2; ++kc) {
#pragma unroll
            for (int s = 0; s < 2; ++s) {
                __builtin_amdgcn_global_load_lds(
                    (const __attribute__((address_space(1))) void*)
                        (aBase + (size_t)s * 16 * KK + k0 + kc * 32),
                    (__attribute__((address_space(3))) void*)
                        (sA + kc * 4096 + (wave * 32 + s * 16) * 32), 16, 0, 0);
                __builtin_amdgcn_global_load_lds(
                    (const __attribute__((address_space(1))) void*)
                        (bBase + (size_t)s * 16 * KK + k0 + kc * 32),
                    (__attribute__((address_space(3))) void*)
                        (sB + kc * 4096 + (wave * 32 + s * 16) * 32), 16, 0, 0);
            }
        }
        __syncthreads();

#pragma unroll
        for (int kc = 0; kc < 2; ++kc) {
            short8 af[4], bfr[4];
#pragma unroll
            for (int i = 0; i < 4; ++i) {
                af[i]  = *(const short8*)(sA + kc * 4096 + (wm * 64 + i * 16 + fr) * 32 + fq * 8);
                bfr[i] = *(const short8*)(sB + kc * 4096 + (wn * 64 + i * 16 + fr) * 32 + fq * 8);
            }
#pragma unroll
            for (int i = 0; i < 4; ++i)
#pragma unroll
                for (int j = 0; j < 4; ++j)
                    acc[i][j] = __builtin_amdgcn_mfma_f32_16x16x32_bf16(
                        af[i], bfr[j], acc[i][j], 0, 0, 0);
        }
        __syncthreads();
    }

    // epilogue: bias + activation -> bf16 gate buffer in LDS
    // gbuf layout: [gate][row 128][hcol 32]
    unsigned short* gbuf = smem;  // 4*128*32*2 = 32 KB
#pragma unroll
    for (int j = 0; j < 4; ++j) {
        int ct   = wn * 64 + j * 16 + fr;   // packed col in tile
        int gate = ct >> 5;                 // uniform per (wn,j)
        int hc   = ct & 31;
        const float* bias = (gate == 0) ? bf_ : (gate == 1) ? bi_
                          : (gate == 2) ? bg_ : bo_;
        float bv = bias[h0 + hc];
#pragma unroll
        for (int i = 0; i < 4; ++i) {
            floatx4 v = acc[i][j];
#pragma unroll
            for (int r = 0; r < 4; ++r) {
                float x = v[r] + bv;
                float a = (gate == 2) ? tanhf(x) : 1.f / (1.f + __expf(-x));
                int row = i * 16 + fq * 4 + r + wm * 64;
                gbuf[gate * 4096 + row * 32 + hc] = f2b(a);
            }
        }
    }
    __syncthreads();

    // combine: c = f*c_prev + i*g ; h = o*tanh(c)   (128 x 32 outputs)
#pragma unroll
    for (int it = 0; it < 16; ++it) {
        int e   = it * 256 + t;
        int row = e >> 5, hc = e & 31;
        float f  = b2f(gbuf[         row * 32 + hc]);
        float ii = b2f(gbuf[ 4096 +  row * 32 + hc]);
        float g  = b2f(gbuf[ 8192 +  row * 32 + hc]);
        float o  = b2f(gbuf[12288 +  row * 32 + hc]);
        size_t gi = (size_t)(m0 + row) * HH + h0 + hc;
        float c = f * cprev[gi] + ii * g;
        float h = o * tanhf(c);
        out[gi] = h;
        out[(size_t)BQ * HH + gi] = c;
    }
}

extern "C" void kernel_launch(void* const* d_in, const int* in_sizes, int n_in,
                              void* d_out, int out_size, void* d_ws, size_t ws_size,
                              hipStream_t stream) {
    const float* input  = (const float*)d_in[0];
    const float* h_prev = (const float*)d_in[1];
    const float* c_prev = (const float*)d_in[2];
    const float* Wf = (const float*)d_in[3];
    const float* bf_ = (const float*)d_in[4];
    const float* Wi = (const float*)d_in[5];
    const float* bi_ = (const float*)d_in[6];
    const float* Wg = (const float*)d_in[7];
    const float* bg_ = (const float*)d_in[8];
    const float* Wo = (const float*)d_in[9];
    const float* bo_ = (const float*)d_in[10];
    float* out = (float*)d_out;

    unsigned short* combined = (unsigned short*)d_ws;                   // 64 MB
    unsigned short* Wpk = (unsigned short*)d_ws + (size_t)BQ * KK;      // 64 MB

    pack_combined<<<dim3(2 * BQ * INF / 8 / 256), 256, 0, stream>>>(
        (const float4*)input, (const float4*)h_prev, combined);
    pack_w<<<dim3(4 * HH * KK / 8 / 256), 256, 0, stream>>>(
        (const float4*)Wf, (const float4*)Wi, (const float4*)Wg, (const float4*)Wo, Wpk);
    lstm_fused<<<dim3(64, 64), 256, 0, stream>>>(
        combined, Wpk, c_prev, bf_, bi_, bg_, bo_, out);
}